// Round 16
// baseline (163.356 us; speedup 1.0000x reference)
//
#include <hip/hip_runtime.h>
#include <hip/hip_fp16.h>
#include <math.h>

#define HDIM 128
#define SCHUNK 256

#if __has_builtin(__builtin_amdgcn_cvt_scalef32_pk_f32_fp4) && \
    __has_builtin(__builtin_amdgcn_cvt_scalef32_pk_fp4_f32)
#define HAVE_FP4 1
#else
#define HAVE_FP4 0
#endif

#if HAVE_FP4
#define QSHIFT 6          // 64B rows (128 x fp4)
#define QS1 8.0f
#define QI1 0.125f
#define QS2 64.0f
#define QI2 0.015625f
#else
#define QSHIFT 7          // 128B rows (128 x fp8 e4m3)
#define QS1 16.0f
#define QI1 0.0625f
#define QS2 16.0f
#define QI2 0.0625f
#endif

typedef _Float16 f16;
typedef __attribute__((ext_vector_type(4))) _Float16 f16x4;
typedef __attribute__((ext_vector_type(8))) _Float16 f16x8;
typedef __attribute__((ext_vector_type(4))) float f32x4;
typedef __attribute__((ext_vector_type(2))) float f32x2;

// ---------------------------------------------------------------- utilities
__device__ __forceinline__ int load_idx(const void* ei, long long E, int which,
                                        long long e, int is64) {
    if (is64) {
        const long long* p = (const long long*)ei;
        return (int)p[(long long)which * E + e];
    } else {
        const int* p = (const int*)ei;
        return p[(long long)which * E + e];
    }
}

__device__ __forceinline__ int detect64(const void* ei) {
    const unsigned* u = (const unsigned*)ei;
    unsigned hi = u[2 * (threadIdx.x & 63) + 1];
    return __all(hi == 0u) ? 1 : 0;
}

__device__ __forceinline__ float fin(float x) {
    if (!(x > -3.0e38f)) return -3.0e38f;  // catches nan and -inf
    if (x > 3.0e38f) return 3.0e38f;
    return x;
}

// ------------------- fused: pos_edges (CSR pass A, 2 edges/thread) + W cvt
__global__ __launch_bounds__(256) void pos_cvt_kernel(
        const void* ei, int* wcur, int* posbuf, long long E, int n,
        int posBlocks, const float* __restrict__ W1,
        const float* __restrict__ W2, f16* __restrict__ W1h,
        f16* __restrict__ W2h) {
    if ((int)blockIdx.x < posBlocks) {
        int is64 = detect64(ei);
        long long base =
            ((long long)blockIdx.x * blockDim.x + threadIdx.x) * 2;
        int d0 = (base < E) ? load_idx(ei, E, 1, base, is64) : -1;
        int d1 = (base + 1 < E) ? load_idx(ei, E, 1, base + 1, is64) : -1;
        int r0 = -1, r1 = -1;
        if ((unsigned)d0 < (unsigned)n) r0 = atomicAdd(&wcur[d0], 1);
        if ((unsigned)d1 < (unsigned)n) r1 = atomicAdd(&wcur[d1], 1);
        if (base < E) posbuf[base] = r0;
        if (base + 1 < E) posbuf[base + 1] = r1;
    } else {
        int gid = ((int)blockIdx.x - posBlocks) * 256 + threadIdx.x;
        if (gid < 4096) {
            float4 v = ((const float4*)W1)[gid];
            ((f16x4*)W1h)[gid] =
                (f16x4){(f16)v.x, (f16)v.y, (f16)v.z, (f16)v.w};
        } else if (gid < 8192) {
            int g = gid - 4096;
            float4 v = ((const float4*)W2)[g];
            ((f16x4*)W2h)[g] =
                (f16x4){(f16)v.x, (f16)v.y, (f16)v.z, (f16)v.w};
        }
    }
}

// -------------------------------- single-kernel scan (deg -> rowstart/dinv)
// Block b: strided-sum deg[0..b*SCHUNK) for its base offset (L2-hot, ~200KB
// worst case), then local inclusive scan of its own chunk.
__global__ __launch_bounds__(SCHUNK) void scan_all_kernel(
        const int* __restrict__ deg, int* __restrict__ rowstart,
        float* __restrict__ dinv, int n, int nb) {
    __shared__ int sd[SCHUNK];
    __shared__ int s_boff;
    int b = blockIdx.x, t = threadIdx.x;
    int lim = b * SCHUNK;
    int ps = 0;
    for (int j = t; j < lim; j += SCHUNK) ps += deg[j];
    sd[t] = ps;
    __syncthreads();
    for (int off = SCHUNK / 2; off > 0; off >>= 1) {
        if (t < off) sd[t] += sd[t + off];
        __syncthreads();
    }
    if (t == 0) s_boff = sd[0];
    __syncthreads();
    int boff = s_boff;
    int i = lim + t;
    int v = (i < n) ? deg[i] : 0;
    sd[t] = v;
    __syncthreads();
    for (int off = 1; off < SCHUNK; off <<= 1) {
        int add = (t >= off) ? sd[t - off] : 0;
        __syncthreads();
        sd[t] += add;
        __syncthreads();
    }
    if (i < n) {
        rowstart[i] = boff + sd[t] - v;
        dinv[i] = rsqrtf((float)(v + 1));
    }
    if (b == nb - 1 && t == SCHUNK - 1) rowstart[n] = boff + sd[t];
}

// ---------------------------------------------------- quantized row helpers
__device__ __forceinline__ f32x2 dec_msg(const unsigned char* p) {
#if HAVE_FP4
    unsigned b = *p;
    return __builtin_amdgcn_cvt_scalef32_pk_f32_fp4(b, 1.0f, 0);
#else
    unsigned short u = *(const unsigned short*)p;
    return __builtin_amdgcn_cvt_pk_f32_fp8((int)u, false);
#endif
}

__device__ __forceinline__ unsigned enc_fp4_pair(float a, float b) {
#if HAVE_FP4
    return __builtin_amdgcn_cvt_scalef32_pk_fp4_f32(0u, a, b, 1.0f, 0);
#else
    (void)a; (void)b; return 0u;
#endif
}

__device__ __forceinline__ unsigned char enc_fp8(float sv) {
    int w = __builtin_amdgcn_cvt_pk_fp8_f32(sv, sv, 0, false);
    return (unsigned char)(w & 0xff);
}

#define QSTORE(sv_, gr_, cc_, cl_)                                             \
    {                                                                          \
        float sv = (sv_);                                                      \
        if (HAVE_FP4) {                                                        \
            float pv = __shfl_xor(sv, 1);                                      \
            if ((gr_) < n && !((cl_) & 1)) {                                   \
                unsigned pb = enc_fp4_pair(sv, pv);                            \
                Yq[((size_t)(gr_) << QSHIFT) + ((cc_) >> 1)] =                 \
                    (unsigned char)(pb & 0xff);                                \
            }                                                                  \
        } else {                                                               \
            if ((gr_) < n) {                                                   \
                Yq[((size_t)(gr_) << QSHIFT) + (cc_)] = enc_fp8(sv);           \
            }                                                                  \
        }                                                                      \
    }

// ---------------------- fused: GEMM layer-1 (MFMA, f32 in) + CSR scatter
__global__ __launch_bounds__(256) void gemm1_scatter_kernel(
        const float* __restrict__ Xf, const f16* __restrict__ Wh,
        const float* __restrict__ dinv, unsigned char* __restrict__ Yq,
        int n, int gemmBlocks, float qs,
        const void* ei, const int* __restrict__ posbuf,
        const int* __restrict__ rowstart, unsigned* __restrict__ selist,
        long long E) {
    __shared__ f16 wT[HDIM][HDIM + 8];
    int t = threadIdx.x;
    if ((int)blockIdx.x >= gemmBlocks) {
        int is64 = detect64(ei);
        long long e =
            (long long)((int)blockIdx.x - gemmBlocks) * blockDim.x + t;
        if (e >= E) return;
        int r = posbuf[e];
        if (r < 0) return;
        int d = load_idx(ei, E, 1, e, is64);
        int s = load_idx(ei, E, 0, e, is64);
        if ((unsigned)s >= (unsigned)n) s = d;
        long long pos = (long long)rowstart[d] + r;
        if (pos >= 0 && pos < E) selist[pos] = (unsigned)s << QSHIFT;
        return;
    }
    {
        int k = t >> 1, c0 = (t & 1) * 64;
        const f16x8* src = (const f16x8*)(Wh + (size_t)k * HDIM + c0);
#pragma unroll
        for (int j = 0; j < 8; ++j) {
            f16x8 v = src[j];
#pragma unroll
            for (int e = 0; e < 8; ++e) wT[c0 + j * 8 + e][k] = v[e];
        }
    }
    __syncthreads();
    int wid = t >> 6, lane = t & 63;
    int cl = lane & 15, kg = lane >> 4;
    int row0 = blockIdx.x * 64 + wid * 16;
    int rA = row0 + cl;
    bool okA = rA < n;
    f32x4 acc[8];
#pragma unroll
    for (int c = 0; c < 8; ++c) acc[c] = (f32x4){0.f, 0.f, 0.f, 0.f};
#pragma unroll
    for (int ks = 0; ks < 4; ++ks) {
        f16x8 a;
        if (okA) {
            const float* ap = Xf + (size_t)rA * HDIM + kg * 8 + ks * 32;
            float4 v0 = *(const float4*)ap;
            float4 v1 = *(const float4*)(ap + 4);
            a = (f16x8){(f16)v0.x, (f16)v0.y, (f16)v0.z, (f16)v0.w,
                        (f16)v1.x, (f16)v1.y, (f16)v1.z, (f16)v1.w};
        } else {
#pragma unroll
            for (int e = 0; e < 8; ++e) a[e] = (f16)0.f;
        }
#pragma unroll
        for (int c = 0; c < 8; ++c) {
            f16x8 b = *(const f16x8*)(&wT[c * 16 + cl][ks * 32 + kg * 8]);
            acc[c] = __builtin_amdgcn_mfma_f32_16x16x32_f16(a, b, acc[c], 0, 0, 0);
        }
    }
    int orow = row0 + kg * 4;
    float dv[4];
#pragma unroll
    for (int j = 0; j < 4; ++j)
        dv[j] = (orow + j < n) ? dinv[orow + j] * qs : 0.f;
#pragma unroll
    for (int c = 0; c < 8; ++c) {
#pragma unroll
        for (int j = 0; j < 4; ++j) {
            int gr = orow + j;
            QSTORE(acc[c][j] * dv[j], gr, c * 16 + cl, cl);
        }
    }
}

// -------------------------------------------- MFMA GEMM layer 2 (fp16 in)
__global__ __launch_bounds__(256) void gemm2_mfma_kernel(
        const f16* __restrict__ Xh, const f16* __restrict__ Wh,
        const float* __restrict__ dinv, unsigned char* __restrict__ Yq,
        int n, float qs) {
    __shared__ f16 wT[HDIM][HDIM + 8];
    int t = threadIdx.x;
    {
        int k = t >> 1, c0 = (t & 1) * 64;
        const f16x8* src = (const f16x8*)(Wh + (size_t)k * HDIM + c0);
#pragma unroll
        for (int j = 0; j < 8; ++j) {
            f16x8 v = src[j];
#pragma unroll
            for (int e = 0; e < 8; ++e) wT[c0 + j * 8 + e][k] = v[e];
        }
    }
    __syncthreads();
    int wid = t >> 6, lane = t & 63;
    int cl = lane & 15, kg = lane >> 4;
    int row0 = blockIdx.x * 64 + wid * 16;
    int rA = row0 + cl;
    bool okA = rA < n;
    f32x4 acc[8];
#pragma unroll
    for (int c = 0; c < 8; ++c) acc[c] = (f32x4){0.f, 0.f, 0.f, 0.f};
#pragma unroll
    for (int ks = 0; ks < 4; ++ks) {
        f16x8 a;
        if (okA) {
            a = *(const f16x8*)(Xh + (size_t)rA * HDIM + kg * 8 + ks * 32);
        } else {
#pragma unroll
            for (int e = 0; e < 8; ++e) a[e] = (f16)0.f;
        }
#pragma unroll
        for (int c = 0; c < 8; ++c) {
            f16x8 b = *(const f16x8*)(&wT[c * 16 + cl][ks * 32 + kg * 8]);
            acc[c] = __builtin_amdgcn_mfma_f32_16x16x32_f16(a, b, acc[c], 0, 0, 0);
        }
    }
    int orow = row0 + kg * 4;
    float dv[4];
#pragma unroll
    for (int j = 0; j < 4; ++j)
        dv[j] = (orow + j < n) ? dinv[orow + j] * qs : 0.f;
#pragma unroll
    for (int c = 0; c < 8; ++c) {
#pragma unroll
        for (int j = 0; j < 4; ++j) {
            int gr = orow + j;
            QSTORE(acc[c][j] * dv[j], gr, c * 16 + cl, cl);
        }
    }
}

// --------------------------------------- paired gather (2 nodes per wave)
#if HAVE_FP4
#define LOFF(lane) ((unsigned)(lane))
#else
#define LOFF(lane) ((unsigned)(lane) * 2u)
#endif

#define BATCH8(acc_, accb_, ii_)                                               \
    {                                                                          \
        const unsigned char* p[8];                                             \
        _Pragma("unroll") for (int j = 0; j < 8; ++j)                          \
            p[j] = Yq + selist[(ii_) + j] + loff;                              \
        f32x2 f0 = dec_msg(p[0]), f1 = dec_msg(p[1]);                          \
        f32x2 f2 = dec_msg(p[2]), f3 = dec_msg(p[3]);                          \
        f32x2 f4 = dec_msg(p[4]), f5 = dec_msg(p[5]);                         \
        f32x2 f6 = dec_msg(p[6]), f7 = dec_msg(p[7]);                         \
        acc_ += (f0 + f1) + (f2 + f3);                                         \
        accb_ += (f4 + f5) + (f6 + f7);                                        \
    }

__device__ __forceinline__ void gather_pair(
        const unsigned char* __restrict__ Yq, const int* __restrict__ rowstart,
        const unsigned* __restrict__ selist, int v0, int v1, int lane,
        f32x2* r0, f32x2* r1) {
    unsigned loff = LOFF(lane);
    f32x2 a0 = dec_msg(Yq + ((size_t)v0 << QSHIFT) + loff);
    f32x2 b0 = (f32x2){0.f, 0.f};
    f32x2 a1 = dec_msg(Yq + ((size_t)v1 << QSHIFT) + loff);
    f32x2 b1 = (f32x2){0.f, 0.f};
    int i0 = __builtin_amdgcn_readfirstlane(rowstart[v0]);
    int e0 = __builtin_amdgcn_readfirstlane(rowstart[v0 + 1]);
    int i1 = __builtin_amdgcn_readfirstlane(rowstart[v1]);
    int e1 = __builtin_amdgcn_readfirstlane(rowstart[v1 + 1]);
    while (i0 + 8 <= e0 && i1 + 8 <= e1) {
        const unsigned char* p0[8];
        const unsigned char* p1[8];
#pragma unroll
        for (int j = 0; j < 8; ++j) p0[j] = Yq + selist[i0 + j] + loff;
#pragma unroll
        for (int j = 0; j < 8; ++j) p1[j] = Yq + selist[i1 + j] + loff;
        f32x2 f0 = dec_msg(p0[0]), f1 = dec_msg(p0[1]);
        f32x2 f2 = dec_msg(p0[2]), f3 = dec_msg(p0[3]);
        f32x2 f4 = dec_msg(p0[4]), f5 = dec_msg(p0[5]);
        f32x2 f6 = dec_msg(p0[6]), f7 = dec_msg(p0[7]);
        f32x2 g0 = dec_msg(p1[0]), g1 = dec_msg(p1[1]);
        f32x2 g2 = dec_msg(p1[2]), g3 = dec_msg(p1[3]);
        f32x2 g4 = dec_msg(p1[4]), g5 = dec_msg(p1[5]);
        f32x2 g6 = dec_msg(p1[6]), g7 = dec_msg(p1[7]);
        a0 += (f0 + f1) + (f2 + f3);
        b0 += (f4 + f5) + (f6 + f7);
        a1 += (g0 + g1) + (g2 + g3);
        b1 += (g4 + g5) + (g6 + g7);
        i0 += 8;
        i1 += 8;
    }
    for (; i0 + 8 <= e0; i0 += 8) BATCH8(a0, b0, i0);
    for (; i0 < e0; ++i0) a0 += dec_msg(Yq + selist[i0] + loff);
    for (; i1 + 8 <= e1; i1 += 8) BATCH8(a1, b1, i1);
    for (; i1 < e1; ++i1) a1 += dec_msg(Yq + selist[i1] + loff);
    *r0 = a0 + b0;
    *r1 = a1 + b1;
}

// -------------------------------------------------------------------- pull
__global__ __launch_bounds__(256) void pull_relu_kernel(
        const unsigned char* __restrict__ Yq, const int* __restrict__ rowstart,
        const unsigned* __restrict__ selist, const float* __restrict__ dinv,
        const float* __restrict__ bias, __half* __restrict__ Bh, int n,
        float qinv) {
    int pw = (int)((blockIdx.x * blockDim.x + threadIdx.x) >> 6);
    int lane = threadIdx.x & 63;
    int v0 = pw * 2, v1 = pw * 2 + 1;
    if (v0 >= n) return;
    bool has1 = v1 < n;
    f32x2 a0, a1;
    gather_pair(Yq, rowstart, selist, v0, has1 ? v1 : v0, lane, &a0, &a1);
    float2 b = ((const float2*)bias)[lane];
    {
        float dv = dinv[v0] * qinv;
        float hx = fmaxf(fmaf(dv, a0.x, b.x), 0.f);
        float hy = fmaxf(fmaf(dv, a0.y, b.y), 0.f);
        ((__half2*)(Bh + (size_t)v0 * HDIM))[lane] = __floats2half2_rn(hx, hy);
    }
    if (has1) {
        float dv = dinv[v1] * qinv;
        float hx = fmaxf(fmaf(dv, a1.x, b.x), 0.f);
        float hy = fmaxf(fmaf(dv, a1.y, b.y), 0.f);
        ((__half2*)(Bh + (size_t)v1 * HDIM))[lane] = __floats2half2_rn(hx, hy);
    }
}

// ------------------------------------------- fused pull (layer 2) + heads
#define SENT (-3.0e38f)
#define BFLY(p) \
    p += __shfl_xor(p, 32); p += __shfl_xor(p, 16); p += __shfl_xor(p, 8); \
    p += __shfl_xor(p, 4);  p += __shfl_xor(p, 2);  p += __shfl_xor(p, 1);

__device__ __forceinline__ void heads_write(
        float hx, float hy, int v, int lane, float4 wd, float4 wu,
        float4 wr0, float4 wr1, const float* __restrict__ bdet,
        const float* __restrict__ bund, const float* __restrict__ broot,
        float* __restrict__ out, int n) {
    float pd0 = hx * wd.x + hy * wd.z;
    float pd1 = hx * wd.y + hy * wd.w;
    float pu0 = hx * wu.x + hy * wu.z;
    float pu1 = hx * wu.y + hy * wu.w;
    float pr0 = hx * wr0.x + hy * wr1.x;
    float pr1 = hx * wr0.y + hy * wr1.y;
    float pr2 = hx * wr0.z + hy * wr1.z;
    float pr3 = hx * wr0.w + hy * wr1.w;
    BFLY(pd0); BFLY(pd1); BFLY(pu0); BFLY(pu1);
    BFLY(pr0); BFLY(pr1); BFLY(pr2); BFLY(pr3);
    if (lane == 0) {
        float d0 = pd0 + bdet[0], d1 = pd1 + bdet[1];
        float u0 = pu0 + bund[0], u1 = pu1 + bund[1];
        float r0 = pr0 + broot[0], r1 = pr1 + broot[1];
        float r2 = pr2 + broot[2], r3 = pr3 + broot[3];
        float m = fmaxf(d0, d1);
        float lse = m + logf(expf(d0 - m) + expf(d1 - m));
        out[(size_t)v * 2 + 0] = fin(d0 - lse);
        out[(size_t)v * 2 + 1] = fin(d1 - lse);
        float* ro = out + 2 * (size_t)n + (size_t)v * 5;
        if (d1 > d0) {  // argmax == 1 (tie -> index 0 -> false)
            float mm = fmaxf(fmaxf(r0, r1), fmaxf(r2, r3));
            float l2 = mm + logf(expf(r0 - mm) + expf(r1 - mm) +
                                 expf(r2 - mm) + expf(r3 - mm));
            ro[0] = SENT;  // reference: -inf (finite sentinel, inf-inf=nan)
            ro[1] = fin(r0 - l2);
            ro[2] = fin(r1 - l2);
            ro[3] = fin(r2 - l2);
            ro[4] = fin(r3 - l2);
        } else {
            float mm = fmaxf(u0, u1);
            float l2 = mm + logf(expf(u0 - mm) + expf(u1 - mm));
            ro[0] = fin(u0 - l2);
            ro[1] = fin(u1 - l2);
            ro[2] = SENT;
            ro[3] = SENT;
            ro[4] = SENT;
        }
    }
}

__global__ __launch_bounds__(256) void pull_heads_kernel(
        const unsigned char* __restrict__ Yq, const int* __restrict__ rowstart,
        const unsigned* __restrict__ selist, const float* __restrict__ dinv,
        const float* __restrict__ bias,
        const float* __restrict__ Wdet, const float* __restrict__ bdet,
        const float* __restrict__ Wund, const float* __restrict__ bund,
        const float* __restrict__ Wroot, const float* __restrict__ broot,
        float* __restrict__ out, int n, float qinv) {
    int pw = (int)((blockIdx.x * blockDim.x + threadIdx.x) >> 6);
    int lane = threadIdx.x & 63;
    int v0 = pw * 2, v1 = pw * 2 + 1;
    if (v0 >= n) return;
    bool has1 = v1 < n;
    f32x2 a0, a1;
    gather_pair(Yq, rowstart, selist, v0, has1 ? v1 : v0, lane, &a0, &a1);
    float2 b = ((const float2*)bias)[lane];
    float4 wd  = ((const float4*)Wdet)[lane];
    float4 wu  = ((const float4*)Wund)[lane];
    float4 wr0 = ((const float4*)Wroot)[2 * lane];
    float4 wr1 = ((const float4*)Wroot)[2 * lane + 1];
    {
        float dv = dinv[v0] * qinv;
        float hx = fmaxf(fmaf(dv, a0.x, b.x), 0.f);
        float hy = fmaxf(fmaf(dv, a0.y, b.y), 0.f);
        heads_write(hx, hy, v0, lane, wd, wu, wr0, wr1, bdet, bund, broot,
                    out, n);
    }
    if (has1) {
        float dv = dinv[v1] * qinv;
        float hx = fmaxf(fmaf(dv, a1.x, b.x), 0.f);
        float hy = fmaxf(fmaf(dv, a1.y, b.y), 0.f);
        heads_write(hx, hy, v1, lane, wd, wu, wr0, wr1, bdet, bund, broot,
                    out, n);
    }
}

__global__ void ws_too_small_kernel(float* out, int n) {
    int i = blockIdx.x * blockDim.x + threadIdx.x;
    if (i < n) out[i] = -12345.0f;  // sentinel: workspace was insufficient
}

// ----------------------------------------------------------------- launch
extern "C" void kernel_launch(void* const* d_in, const int* in_sizes, int n_in,
                              void* d_out, int out_size, void* d_ws,
                              size_t ws_size, hipStream_t stream) {
    const float* x     = (const float*)d_in[0];
    const void*  ei    = d_in[1];
    const float* W1    = (const float*)d_in[2];
    const float* b1    = (const float*)d_in[3];
    const float* W2    = (const float*)d_in[4];
    const float* b2    = (const float*)d_in[5];
    const float* Wdet  = (const float*)d_in[6];
    const float* bdet  = (const float*)d_in[7];
    const float* Wund  = (const float*)d_in[8];
    const float* bund  = (const float*)d_in[9];
    const float* Wroot = (const float*)d_in[10];
    const float* broot = (const float*)d_in[11];
    int N = in_sizes[0] / HDIM;       // 50000
    long long E = in_sizes[1] / 2;    // 800000
    float* out = (float*)d_out;
    int nb = (N + SCHUNK - 1) / SCHUNK;

    size_t off = 0;
    auto carve = [&](size_t bytes) -> void* {
        void* p = (char*)d_ws + off;
        off += (bytes + 255) & ~(size_t)255;
        return p;
    };
    unsigned char* Yq   = (unsigned char*)carve((size_t)N * HDIM);
    __half*   Bh       = (__half*)carve((size_t)N * HDIM * 2);
    f16*      W1h      = (f16*)carve((size_t)HDIM * HDIM * 2);
    f16*      W2h      = (f16*)carve((size_t)HDIM * HDIM * 2);
    float*    dinv     = (float*)carve((size_t)N * 4);
    int*      rowstart = (int*)carve((size_t)(N + 1) * 4);
    int*      wcur     = (int*)carve((size_t)N * 4);
    int*      posbuf   = (int*)carve((size_t)E * 4);
    unsigned* selist   = (unsigned*)carve((size_t)E * 4);

    if (off > ws_size) {
        ws_too_small_kernel<<<(out_size + 255) / 256, 256, 0, stream>>>(out, out_size);
        return;
    }

    int e1grid = (int)((E + 255) / 256);            // scatter grid (1/thread)
    int posgrid = (int)((E + 511) / 512);           // pos grid (2/thread)
    int gemm_grid = (N + 63) / 64;
    int pairs = (N + 1) / 2;
    int pull_grid = (pairs + 3) / 4;  // 4 waves (node pairs) per block

    // CSR pass A (+ W cvt fused)
    hipMemsetAsync(wcur, 0, (size_t)N * 4, stream);
    pos_cvt_kernel<<<posgrid + 32, 256, 0, stream>>>(ei, wcur, posbuf, E, N,
                                                     posgrid, W1, W2, W1h,
                                                     W2h);
    scan_all_kernel<<<nb, SCHUNK, 0, stream>>>(wcur, rowstart, dinv, N, nb);

    // layer-1 GEMM + CSR pass B fused (independent; overlap)
    gemm1_scatter_kernel<<<gemm_grid + e1grid, 256, 0, stream>>>(
        x, W1h, dinv, Yq, N, gemm_grid, QS1, ei, posbuf, rowstart, selist, E);

    // layer 1 pull (2 nodes/wave)
    pull_relu_kernel<<<pull_grid, 256, 0, stream>>>(Yq, rowstart, selist,
                                                    dinv, b1, Bh, N, QI1);
    // layer 2 GEMM + fused pull + heads -> out
    gemm2_mfma_kernel<<<gemm_grid, 256, 0, stream>>>((const f16*)Bh, W2h,
                                                     dinv, Yq, N, QS2);
    pull_heads_kernel<<<pull_grid, 256, 0, stream>>>(Yq, rowstart, selist,
                                                     dinv, b2, Wdet, bdet,
                                                     Wund, bund, Wroot, broot,
                                                     out, N, QI2);
}

// Round 17
// 162.611 us; speedup vs baseline: 1.0046x; 1.0046x over previous
//
#include <hip/hip_runtime.h>
#include <hip/hip_fp16.h>
#include <math.h>

#define HDIM 128
#define SCHUNK 256

#if __has_builtin(__builtin_amdgcn_cvt_scalef32_pk_f32_fp4) && \
    __has_builtin(__builtin_amdgcn_cvt_scalef32_pk_fp4_f32)
#define HAVE_FP4 1
#else
#define HAVE_FP4 0
#endif

#if HAVE_FP4
#define QSHIFT 6          // 64B rows (128 x fp4)
#define QS1 8.0f
#define QI1 0.125f
#define QS2 64.0f
#define QI2 0.015625f
#else
#define QSHIFT 7          // 128B rows (128 x fp8 e4m3)
#define QS1 16.0f
#define QI1 0.0625f
#define QS2 16.0f
#define QI2 0.0625f
#endif

typedef _Float16 f16;
typedef __attribute__((ext_vector_type(4))) _Float16 f16x4;
typedef __attribute__((ext_vector_type(8))) _Float16 f16x8;
typedef __attribute__((ext_vector_type(4))) float f32x4;
typedef __attribute__((ext_vector_type(2))) float f32x2;

// ---------------------------------------------------------------- utilities
__device__ __forceinline__ int load_idx(const void* ei, long long E, int which,
                                        long long e, int is64) {
    if (is64) {
        const long long* p = (const long long*)ei;
        return (int)p[(long long)which * E + e];
    } else {
        const int* p = (const int*)ei;
        return p[(long long)which * E + e];
    }
}

__device__ __forceinline__ int detect64(const void* ei) {
    const unsigned* u = (const unsigned*)ei;
    unsigned hi = u[2 * (threadIdx.x & 63) + 1];
    return __all(hi == 0u) ? 1 : 0;
}

__device__ __forceinline__ float fin(float x) {
    if (!(x > -3.0e38f)) return -3.0e38f;  // catches nan and -inf
    if (x > 3.0e38f) return 3.0e38f;
    return x;
}

// ------------------- fused: pos_edges (CSR pass A, 1 edge/thread) + W cvt
// NOTE (round 16 lesson): the atomic-rank pass is TLP-bound, not ILP-bound.
// 2 edges/thread tripled its time (44us vs <41); keep 1 edge/thread.
__global__ __launch_bounds__(256) void pos_cvt_kernel(
        const void* ei, int* wcur, int* posbuf, long long E, int n,
        int posBlocks, const float* __restrict__ W1,
        const float* __restrict__ W2, f16* __restrict__ W1h,
        f16* __restrict__ W2h) {
    if ((int)blockIdx.x < posBlocks) {
        int is64 = detect64(ei);
        long long e = (long long)blockIdx.x * blockDim.x + threadIdx.x;
        if (e >= E) return;
        int d = load_idx(ei, E, 1, e, is64);
        int r = -1;
        if ((unsigned)d < (unsigned)n) r = atomicAdd(&wcur[d], 1);
        posbuf[e] = r;
    } else {
        int gid = ((int)blockIdx.x - posBlocks) * 256 + threadIdx.x;
        if (gid < 4096) {
            float4 v = ((const float4*)W1)[gid];
            ((f16x4*)W1h)[gid] =
                (f16x4){(f16)v.x, (f16)v.y, (f16)v.z, (f16)v.w};
        } else if (gid < 8192) {
            int g = gid - 4096;
            float4 v = ((const float4*)W2)[g];
            ((f16x4*)W2h)[g] =
                (f16x4){(f16)v.x, (f16)v.y, (f16)v.z, (f16)v.w};
        }
    }
}

// -------------------------------- single-kernel scan (deg -> rowstart/dinv)
__global__ __launch_bounds__(SCHUNK) void scan_all_kernel(
        const int* __restrict__ deg, int* __restrict__ rowstart,
        float* __restrict__ dinv, int n, int nb) {
    __shared__ int sd[SCHUNK];
    __shared__ int s_boff;
    int b = blockIdx.x, t = threadIdx.x;
    int lim = b * SCHUNK;
    int ps = 0;
    for (int j = t; j < lim; j += SCHUNK) ps += deg[j];
    sd[t] = ps;
    __syncthreads();
    for (int off = SCHUNK / 2; off > 0; off >>= 1) {
        if (t < off) sd[t] += sd[t + off];
        __syncthreads();
    }
    if (t == 0) s_boff = sd[0];
    __syncthreads();
    int boff = s_boff;
    int i = lim + t;
    int v = (i < n) ? deg[i] : 0;
    sd[t] = v;
    __syncthreads();
    for (int off = 1; off < SCHUNK; off <<= 1) {
        int add = (t >= off) ? sd[t - off] : 0;
        __syncthreads();
        sd[t] += add;
        __syncthreads();
    }
    if (i < n) {
        rowstart[i] = boff + sd[t] - v;
        dinv[i] = rsqrtf((float)(v + 1));
    }
    if (b == nb - 1 && t == SCHUNK - 1) rowstart[n] = boff + sd[t];
}

// ---------------------------------------------------- quantized row helpers
__device__ __forceinline__ f32x2 dec_msg(const unsigned char* p) {
#if HAVE_FP4
    unsigned b = *p;
    return __builtin_amdgcn_cvt_scalef32_pk_f32_fp4(b, 1.0f, 0);
#else
    unsigned short u = *(const unsigned short*)p;
    return __builtin_amdgcn_cvt_pk_f32_fp8((int)u, false);
#endif
}

__device__ __forceinline__ unsigned enc_fp4_pair(float a, float b) {
#if HAVE_FP4
    return __builtin_amdgcn_cvt_scalef32_pk_fp4_f32(0u, a, b, 1.0f, 0);
#else
    (void)a; (void)b; return 0u;
#endif
}

__device__ __forceinline__ unsigned char enc_fp8(float sv) {
    int w = __builtin_amdgcn_cvt_pk_fp8_f32(sv, sv, 0, false);
    return (unsigned char)(w & 0xff);
}

#define QSTORE(sv_, gr_, cc_, cl_)                                             \
    {                                                                          \
        float sv = (sv_);                                                      \
        if (HAVE_FP4) {                                                        \
            float pv = __shfl_xor(sv, 1);                                      \
            if ((gr_) < n && !((cl_) & 1)) {                                   \
                unsigned pb = enc_fp4_pair(sv, pv);                            \
                Yq[((size_t)(gr_) << QSHIFT) + ((cc_) >> 1)] =                 \
                    (unsigned char)(pb & 0xff);                                \
            }                                                                  \
        } else {                                                               \
            if ((gr_) < n) {                                                   \
                Yq[((size_t)(gr_) << QSHIFT) + (cc_)] = enc_fp8(sv);           \
            }                                                                  \
        }                                                                      \
    }

// ---------------------- fused: GEMM layer-1 (MFMA, f32 in) + CSR scatter
__global__ __launch_bounds__(256) void gemm1_scatter_kernel(
        const float* __restrict__ Xf, const f16* __restrict__ Wh,
        const float* __restrict__ dinv, unsigned char* __restrict__ Yq,
        int n, int gemmBlocks, float qs,
        const void* ei, const int* __restrict__ posbuf,
        const int* __restrict__ rowstart, unsigned* __restrict__ selist,
        long long E) {
    __shared__ f16 wT[HDIM][HDIM + 8];
    int t = threadIdx.x;
    if ((int)blockIdx.x >= gemmBlocks) {
        int is64 = detect64(ei);
        long long e =
            (long long)((int)blockIdx.x - gemmBlocks) * blockDim.x + t;
        if (e >= E) return;
        int r = posbuf[e];
        if (r < 0) return;
        int d = load_idx(ei, E, 1, e, is64);
        int s = load_idx(ei, E, 0, e, is64);
        if ((unsigned)s >= (unsigned)n) s = d;
        long long pos = (long long)rowstart[d] + r;
        if (pos >= 0 && pos < E) selist[pos] = (unsigned)s << QSHIFT;
        return;
    }
    {
        int k = t >> 1, c0 = (t & 1) * 64;
        const f16x8* src = (const f16x8*)(Wh + (size_t)k * HDIM + c0);
#pragma unroll
        for (int j = 0; j < 8; ++j) {
            f16x8 v = src[j];
#pragma unroll
            for (int e = 0; e < 8; ++e) wT[c0 + j * 8 + e][k] = v[e];
        }
    }
    __syncthreads();
    int wid = t >> 6, lane = t & 63;
    int cl = lane & 15, kg = lane >> 4;
    int row0 = blockIdx.x * 64 + wid * 16;
    int rA = row0 + cl;
    bool okA = rA < n;
    f32x4 acc[8];
#pragma unroll
    for (int c = 0; c < 8; ++c) acc[c] = (f32x4){0.f, 0.f, 0.f, 0.f};
#pragma unroll
    for (int ks = 0; ks < 4; ++ks) {
        f16x8 a;
        if (okA) {
            const float* ap = Xf + (size_t)rA * HDIM + kg * 8 + ks * 32;
            float4 v0 = *(const float4*)ap;
            float4 v1 = *(const float4*)(ap + 4);
            a = (f16x8){(f16)v0.x, (f16)v0.y, (f16)v0.z, (f16)v0.w,
                        (f16)v1.x, (f16)v1.y, (f16)v1.z, (f16)v1.w};
        } else {
#pragma unroll
            for (int e = 0; e < 8; ++e) a[e] = (f16)0.f;
        }
#pragma unroll
        for (int c = 0; c < 8; ++c) {
            f16x8 b = *(const f16x8*)(&wT[c * 16 + cl][ks * 32 + kg * 8]);
            acc[c] = __builtin_amdgcn_mfma_f32_16x16x32_f16(a, b, acc[c], 0, 0, 0);
        }
    }
    int orow = row0 + kg * 4;
    float dv[4];
#pragma unroll
    for (int j = 0; j < 4; ++j)
        dv[j] = (orow + j < n) ? dinv[orow + j] * qs : 0.f;
#pragma unroll
    for (int c = 0; c < 8; ++c) {
#pragma unroll
        for (int j = 0; j < 4; ++j) {
            int gr = orow + j;
            QSTORE(acc[c][j] * dv[j], gr, c * 16 + cl, cl);
        }
    }
}

// -------------------------------------------- MFMA GEMM layer 2 (fp16 in)
__global__ __launch_bounds__(256) void gemm2_mfma_kernel(
        const f16* __restrict__ Xh, const f16* __restrict__ Wh,
        const float* __restrict__ dinv, unsigned char* __restrict__ Yq,
        int n, float qs) {
    __shared__ f16 wT[HDIM][HDIM + 8];
    int t = threadIdx.x;
    {
        int k = t >> 1, c0 = (t & 1) * 64;
        const f16x8* src = (const f16x8*)(Wh + (size_t)k * HDIM + c0);
#pragma unroll
        for (int j = 0; j < 8; ++j) {
            f16x8 v = src[j];
#pragma unroll
            for (int e = 0; e < 8; ++e) wT[c0 + j * 8 + e][k] = v[e];
        }
    }
    __syncthreads();
    int wid = t >> 6, lane = t & 63;
    int cl = lane & 15, kg = lane >> 4;
    int row0 = blockIdx.x * 64 + wid * 16;
    int rA = row0 + cl;
    bool okA = rA < n;
    f32x4 acc[8];
#pragma unroll
    for (int c = 0; c < 8; ++c) acc[c] = (f32x4){0.f, 0.f, 0.f, 0.f};
#pragma unroll
    for (int ks = 0; ks < 4; ++ks) {
        f16x8 a;
        if (okA) {
            a = *(const f16x8*)(Xh + (size_t)rA * HDIM + kg * 8 + ks * 32);
        } else {
#pragma unroll
            for (int e = 0; e < 8; ++e) a[e] = (f16)0.f;
        }
#pragma unroll
        for (int c = 0; c < 8; ++c) {
            f16x8 b = *(const f16x8*)(&wT[c * 16 + cl][ks * 32 + kg * 8]);
            acc[c] = __builtin_amdgcn_mfma_f32_16x16x32_f16(a, b, acc[c], 0, 0, 0);
        }
    }
    int orow = row0 + kg * 4;
    float dv[4];
#pragma unroll
    for (int j = 0; j < 4; ++j)
        dv[j] = (orow + j < n) ? dinv[orow + j] * qs : 0.f;
#pragma unroll
    for (int c = 0; c < 8; ++c) {
#pragma unroll
        for (int j = 0; j < 4; ++j) {
            int gr = orow + j;
            QSTORE(acc[c][j] * dv[j], gr, c * 16 + cl, cl);
        }
    }
}

// --------------------------------------- paired gather (2 nodes per wave)
#if HAVE_FP4
#define LOFF(lane) ((unsigned)(lane))
#else
#define LOFF(lane) ((unsigned)(lane) * 2u)
#endif

#define BATCH8(acc_, accb_, ii_)                                               \
    {                                                                          \
        const unsigned char* p[8];                                             \
        _Pragma("unroll") for (int j = 0; j < 8; ++j)                          \
            p[j] = Yq + selist[(ii_) + j] + loff;                              \
        f32x2 f0 = dec_msg(p[0]), f1 = dec_msg(p[1]);                          \
        f32x2 f2 = dec_msg(p[2]), f3 = dec_msg(p[3]);                          \
        f32x2 f4 = dec_msg(p[4]), f5 = dec_msg(p[5]);                         \
        f32x2 f6 = dec_msg(p[6]), f7 = dec_msg(p[7]);                         \
        acc_ += (f0 + f1) + (f2 + f3);                                         \
        accb_ += (f4 + f5) + (f6 + f7);                                        \
    }

__device__ __forceinline__ void gather_pair(
        const unsigned char* __restrict__ Yq, const int* __restrict__ rowstart,
        const unsigned* __restrict__ selist, int v0, int v1, int lane,
        f32x2* r0, f32x2* r1) {
    unsigned loff = LOFF(lane);
    f32x2 a0 = dec_msg(Yq + ((size_t)v0 << QSHIFT) + loff);
    f32x2 b0 = (f32x2){0.f, 0.f};
    f32x2 a1 = dec_msg(Yq + ((size_t)v1 << QSHIFT) + loff);
    f32x2 b1 = (f32x2){0.f, 0.f};
    int i0 = __builtin_amdgcn_readfirstlane(rowstart[v0]);
    int e0 = __builtin_amdgcn_readfirstlane(rowstart[v0 + 1]);
    int i1 = __builtin_amdgcn_readfirstlane(rowstart[v1]);
    int e1 = __builtin_amdgcn_readfirstlane(rowstart[v1 + 1]);
    while (i0 + 8 <= e0 && i1 + 8 <= e1) {
        const unsigned char* p0[8];
        const unsigned char* p1[8];
#pragma unroll
        for (int j = 0; j < 8; ++j) p0[j] = Yq + selist[i0 + j] + loff;
#pragma unroll
        for (int j = 0; j < 8; ++j) p1[j] = Yq + selist[i1 + j] + loff;
        f32x2 f0 = dec_msg(p0[0]), f1 = dec_msg(p0[1]);
        f32x2 f2 = dec_msg(p0[2]), f3 = dec_msg(p0[3]);
        f32x2 f4 = dec_msg(p0[4]), f5 = dec_msg(p0[5]);
        f32x2 f6 = dec_msg(p0[6]), f7 = dec_msg(p0[7]);
        f32x2 g0 = dec_msg(p1[0]), g1 = dec_msg(p1[1]);
        f32x2 g2 = dec_msg(p1[2]), g3 = dec_msg(p1[3]);
        f32x2 g4 = dec_msg(p1[4]), g5 = dec_msg(p1[5]);
        f32x2 g6 = dec_msg(p1[6]), g7 = dec_msg(p1[7]);
        a0 += (f0 + f1) + (f2 + f3);
        b0 += (f4 + f5) + (f6 + f7);
        a1 += (g0 + g1) + (g2 + g3);
        b1 += (g4 + g5) + (g6 + g7);
        i0 += 8;
        i1 += 8;
    }
    for (; i0 + 8 <= e0; i0 += 8) BATCH8(a0, b0, i0);
    for (; i0 < e0; ++i0) a0 += dec_msg(Yq + selist[i0] + loff);
    for (; i1 + 8 <= e1; i1 += 8) BATCH8(a1, b1, i1);
    for (; i1 < e1; ++i1) a1 += dec_msg(Yq + selist[i1] + loff);
    *r0 = a0 + b0;
    *r1 = a1 + b1;
}

// -------------------------------------------------------------------- pull
__global__ __launch_bounds__(256) void pull_relu_kernel(
        const unsigned char* __restrict__ Yq, const int* __restrict__ rowstart,
        const unsigned* __restrict__ selist, const float* __restrict__ dinv,
        const float* __restrict__ bias, __half* __restrict__ Bh, int n,
        float qinv) {
    int pw = (int)((blockIdx.x * blockDim.x + threadIdx.x) >> 6);
    int lane = threadIdx.x & 63;
    int v0 = pw * 2, v1 = pw * 2 + 1;
    if (v0 >= n) return;
    bool has1 = v1 < n;
    f32x2 a0, a1;
    gather_pair(Yq, rowstart, selist, v0, has1 ? v1 : v0, lane, &a0, &a1);
    float2 b = ((const float2*)bias)[lane];
    {
        float dv = dinv[v0] * qinv;
        float hx = fmaxf(fmaf(dv, a0.x, b.x), 0.f);
        float hy = fmaxf(fmaf(dv, a0.y, b.y), 0.f);
        ((__half2*)(Bh + (size_t)v0 * HDIM))[lane] = __floats2half2_rn(hx, hy);
    }
    if (has1) {
        float dv = dinv[v1] * qinv;
        float hx = fmaxf(fmaf(dv, a1.x, b.x), 0.f);
        float hy = fmaxf(fmaf(dv, a1.y, b.y), 0.f);
        ((__half2*)(Bh + (size_t)v1 * HDIM))[lane] = __floats2half2_rn(hx, hy);
    }
}

// ------------------------------------------- fused pull (layer 2) + heads
#define SENT (-3.0e38f)
#define BFLY(p) \
    p += __shfl_xor(p, 32); p += __shfl_xor(p, 16); p += __shfl_xor(p, 8); \
    p += __shfl_xor(p, 4);  p += __shfl_xor(p, 2);  p += __shfl_xor(p, 1);

__device__ __forceinline__ void heads_write(
        float hx, float hy, int v, int lane, float4 wd, float4 wu,
        float4 wr0, float4 wr1, const float* __restrict__ bdet,
        const float* __restrict__ bund, const float* __restrict__ broot,
        float* __restrict__ out, int n) {
    float pd0 = hx * wd.x + hy * wd.z;
    float pd1 = hx * wd.y + hy * wd.w;
    float pu0 = hx * wu.x + hy * wu.z;
    float pu1 = hx * wu.y + hy * wu.w;
    float pr0 = hx * wr0.x + hy * wr1.x;
    float pr1 = hx * wr0.y + hy * wr1.y;
    float pr2 = hx * wr0.z + hy * wr1.z;
    float pr3 = hx * wr0.w + hy * wr1.w;
    BFLY(pd0); BFLY(pd1); BFLY(pu0); BFLY(pu1);
    BFLY(pr0); BFLY(pr1); BFLY(pr2); BFLY(pr3);
    if (lane == 0) {
        float d0 = pd0 + bdet[0], d1 = pd1 + bdet[1];
        float u0 = pu0 + bund[0], u1 = pu1 + bund[1];
        float r0 = pr0 + broot[0], r1 = pr1 + broot[1];
        float r2 = pr2 + broot[2], r3 = pr3 + broot[3];
        float m = fmaxf(d0, d1);
        float lse = m + logf(expf(d0 - m) + expf(d1 - m));
        out[(size_t)v * 2 + 0] = fin(d0 - lse);
        out[(size_t)v * 2 + 1] = fin(d1 - lse);
        float* ro = out + 2 * (size_t)n + (size_t)v * 5;
        if (d1 > d0) {  // argmax == 1 (tie -> index 0 -> false)
            float mm = fmaxf(fmaxf(r0, r1), fmaxf(r2, r3));
            float l2 = mm + logf(expf(r0 - mm) + expf(r1 - mm) +
                                 expf(r2 - mm) + expf(r3 - mm));
            ro[0] = SENT;  // reference: -inf (finite sentinel, inf-inf=nan)
            ro[1] = fin(r0 - l2);
            ro[2] = fin(r1 - l2);
            ro[3] = fin(r2 - l2);
            ro[4] = fin(r3 - l2);
        } else {
            float mm = fmaxf(u0, u1);
            float l2 = mm + logf(expf(u0 - mm) + expf(u1 - mm));
            ro[0] = fin(u0 - l2);
            ro[1] = fin(u1 - l2);
            ro[2] = SENT;
            ro[3] = SENT;
            ro[4] = SENT;
        }
    }
}

__global__ __launch_bounds__(256) void pull_heads_kernel(
        const unsigned char* __restrict__ Yq, const int* __restrict__ rowstart,
        const unsigned* __restrict__ selist, const float* __restrict__ dinv,
        const float* __restrict__ bias,
        const float* __restrict__ Wdet, const float* __restrict__ bdet,
        const float* __restrict__ Wund, const float* __restrict__ bund,
        const float* __restrict__ Wroot, const float* __restrict__ broot,
        float* __restrict__ out, int n, float qinv) {
    int pw = (int)((blockIdx.x * blockDim.x + threadIdx.x) >> 6);
    int lane = threadIdx.x & 63;
    int v0 = pw * 2, v1 = pw * 2 + 1;
    if (v0 >= n) return;
    bool has1 = v1 < n;
    f32x2 a0, a1;
    gather_pair(Yq, rowstart, selist, v0, has1 ? v1 : v0, lane, &a0, &a1);
    float2 b = ((const float2*)bias)[lane];
    float4 wd  = ((const float4*)Wdet)[lane];
    float4 wu  = ((const float4*)Wund)[lane];
    float4 wr0 = ((const float4*)Wroot)[2 * lane];
    float4 wr1 = ((const float4*)Wroot)[2 * lane + 1];
    {
        float dv = dinv[v0] * qinv;
        float hx = fmaxf(fmaf(dv, a0.x, b.x), 0.f);
        float hy = fmaxf(fmaf(dv, a0.y, b.y), 0.f);
        heads_write(hx, hy, v0, lane, wd, wu, wr0, wr1, bdet, bund, broot,
                    out, n);
    }
    if (has1) {
        float dv = dinv[v1] * qinv;
        float hx = fmaxf(fmaf(dv, a1.x, b.x), 0.f);
        float hy = fmaxf(fmaf(dv, a1.y, b.y), 0.f);
        heads_write(hx, hy, v1, lane, wd, wu, wr0, wr1, bdet, bund, broot,
                    out, n);
    }
}

__global__ void ws_too_small_kernel(float* out, int n) {
    int i = blockIdx.x * blockDim.x + threadIdx.x;
    if (i < n) out[i] = -12345.0f;  // sentinel: workspace was insufficient
}

// ----------------------------------------------------------------- launch
extern "C" void kernel_launch(void* const* d_in, const int* in_sizes, int n_in,
                              void* d_out, int out_size, void* d_ws,
                              size_t ws_size, hipStream_t stream) {
    const float* x     = (const float*)d_in[0];
    const void*  ei    = d_in[1];
    const float* W1    = (const float*)d_in[2];
    const float* b1    = (const float*)d_in[3];
    const float* W2    = (const float*)d_in[4];
    const float* b2    = (const float*)d_in[5];
    const float* Wdet  = (const float*)d_in[6];
    const float* bdet  = (const float*)d_in[7];
    const float* Wund  = (const float*)d_in[8];
    const float* bund  = (const float*)d_in[9];
    const float* Wroot = (const float*)d_in[10];
    const float* broot = (const float*)d_in[11];
    int N = in_sizes[0] / HDIM;       // 50000
    long long E = in_sizes[1] / 2;    // 800000
    float* out = (float*)d_out;
    int nb = (N + SCHUNK - 1) / SCHUNK;

    size_t off = 0;
    auto carve = [&](size_t bytes) -> void* {
        void* p = (char*)d_ws + off;
        off += (bytes + 255) & ~(size_t)255;
        return p;
    };
    unsigned char* Yq   = (unsigned char*)carve((size_t)N * HDIM);
    __half*   Bh       = (__half*)carve((size_t)N * HDIM * 2);
    f16*      W1h      = (f16*)carve((size_t)HDIM * HDIM * 2);
    f16*      W2h      = (f16*)carve((size_t)HDIM * HDIM * 2);
    float*    dinv     = (float*)carve((size_t)N * 4);
    int*      rowstart = (int*)carve((size_t)(N + 1) * 4);
    int*      wcur     = (int*)carve((size_t)N * 4);
    int*      posbuf   = (int*)carve((size_t)E * 4);
    unsigned* selist   = (unsigned*)carve((size_t)E * 4);

    if (off > ws_size) {
        ws_too_small_kernel<<<(out_size + 255) / 256, 256, 0, stream>>>(out, out_size);
        return;
    }

    int e1grid = (int)((E + 255) / 256);            // 1 edge/thread grids
    int gemm_grid = (N + 63) / 64;
    int pairs = (N + 1) / 2;
    int pull_grid = (pairs + 3) / 4;  // 4 waves (node pairs) per block

    // CSR pass A (+ W cvt fused)
    hipMemsetAsync(wcur, 0, (size_t)N * 4, stream);
    pos_cvt_kernel<<<e1grid + 32, 256, 0, stream>>>(ei, wcur, posbuf, E, N,
                                                    e1grid, W1, W2, W1h, W2h);
    scan_all_kernel<<<nb, SCHUNK, 0, stream>>>(wcur, rowstart, dinv, N, nb);

    // layer-1 GEMM + CSR pass B fused (independent; overlap)
    gemm1_scatter_kernel<<<gemm_grid + e1grid, 256, 0, stream>>>(
        x, W1h, dinv, Yq, N, gemm_grid, QS1, ei, posbuf, rowstart, selist, E);

    // layer 1 pull (2 nodes/wave)
    pull_relu_kernel<<<pull_grid, 256, 0, stream>>>(Yq, rowstart, selist,
                                                    dinv, b1, Bh, N, QI1);
    // layer 2 GEMM + fused pull + heads -> out
    gemm2_mfma_kernel<<<gemm_grid, 256, 0, stream>>>((const f16*)Bh, W2h,
                                                     dinv, Yq, N, QS2);
    pull_heads_kernel<<<pull_grid, 256, 0, stream>>>(Yq, rowstart, selist,
                                                     dinv, b2, Wdet, bdet,
                                                     Wund, bund, Wroot, broot,
                                                     out, N, QI2);
}

// Round 18
// 139.522 us; speedup vs baseline: 1.1708x; 1.1655x over previous
//
#include <hip/hip_runtime.h>
#include <hip/hip_fp16.h>
#include <math.h>

#define HDIM 128
#define SCHUNK 256

#if __has_builtin(__builtin_amdgcn_cvt_scalef32_pk_f32_fp4) && \
    __has_builtin(__builtin_amdgcn_cvt_scalef32_pk_fp4_f32)
#define HAVE_FP4 1
#else
#define HAVE_FP4 0
#endif

#if HAVE_FP4
#define QSHIFT 6          // 64B rows (128 x fp4)
#define QS1 8.0f
#define QI1 0.125f
#define QS2 64.0f
#define QI2 0.015625f
#else
#define QSHIFT 7          // 128B rows (128 x fp8 e4m3)
#define QS1 16.0f
#define QI1 0.0625f
#define QS2 16.0f
#define QI2 0.0625f
#endif

typedef _Float16 f16;
typedef __attribute__((ext_vector_type(4))) _Float16 f16x4;
typedef __attribute__((ext_vector_type(8))) _Float16 f16x8;
typedef __attribute__((ext_vector_type(4))) float f32x4;
typedef __attribute__((ext_vector_type(2))) float f32x2;

// ---------------------------------------------------------------- utilities
__device__ __forceinline__ int load_idx(const void* ei, long long E, int which,
                                        long long e, int is64) {
    if (is64) {
        const long long* p = (const long long*)ei;
        return (int)p[(long long)which * E + e];
    } else {
        const int* p = (const int*)ei;
        return p[(long long)which * E + e];
    }
}

__device__ __forceinline__ int detect64(const void* ei) {
    const unsigned* u = (const unsigned*)ei;
    unsigned hi = u[2 * (threadIdx.x & 63) + 1];
    return __all(hi == 0u) ? 1 : 0;
}

__device__ __forceinline__ float fin(float x) {
    if (!(x > -3.0e38f)) return -3.0e38f;  // catches nan and -inf
    if (x > 3.0e38f) return 3.0e38f;
    return x;
}

// ------------------- fused: pos_edges (CSR pass A, 1 edge/thread) + W cvt
// Round-16/17 lessons: (a) atomic-rank pass is TLP-bound -- keep 1
// edge/thread; (b) the per-block strided-prefix "single-kernel scan" has a
// serial L2-latency chain ~16us on tail blocks -- keep the 2-kernel scan.
__global__ __launch_bounds__(256) void pos_cvt_kernel(
        const void* ei, int* wcur, int* posbuf, long long E, int n,
        int posBlocks, const float* __restrict__ W1,
        const float* __restrict__ W2, f16* __restrict__ W1h,
        f16* __restrict__ W2h) {
    if ((int)blockIdx.x < posBlocks) {
        int is64 = detect64(ei);
        long long e = (long long)blockIdx.x * blockDim.x + threadIdx.x;
        if (e >= E) return;
        int d = load_idx(ei, E, 1, e, is64);
        int r = -1;
        if ((unsigned)d < (unsigned)n) r = atomicAdd(&wcur[d], 1);
        posbuf[e] = r;
    } else {
        int gid = ((int)blockIdx.x - posBlocks) * 256 + threadIdx.x;
        if (gid < 4096) {
            float4 v = ((const float4*)W1)[gid];
            ((f16x4*)W1h)[gid] =
                (f16x4){(f16)v.x, (f16)v.y, (f16)v.z, (f16)v.w};
        } else if (gid < 8192) {
            int g = gid - 4096;
            float4 v = ((const float4*)W2)[g];
            ((f16x4*)W2h)[g] =
                (f16x4){(f16)v.x, (f16)v.y, (f16)v.z, (f16)v.w};
        }
    }
}

// ---------------------------------------------- 2-kernel multi-block scan
__global__ __launch_bounds__(SCHUNK) void scan_p1_kernel(
        const int* __restrict__ deg, int* __restrict__ bsum, int n) {
    __shared__ int sd[SCHUNK];
    int b = blockIdx.x, t = threadIdx.x;
    int i = b * SCHUNK + t;
    sd[t] = (i < n) ? deg[i] : 0;
    __syncthreads();
    for (int off = SCHUNK / 2; off > 0; off >>= 1) {
        if (t < off) sd[t] += sd[t + off];
        __syncthreads();
    }
    if (t == 0) bsum[b] = sd[0];
}

// Fused p2+p3: each block reduces bsum[0..b) itself (196 L2-hit ints, ONE
// strided pass), then local scan + write rowstart / dinv.
__global__ __launch_bounds__(SCHUNK) void scan_p23_kernel(
        const int* __restrict__ deg, const int* __restrict__ bsum, int nb,
        int* __restrict__ rowstart, float* __restrict__ dinv, int n) {
    __shared__ int sd[SCHUNK];
    __shared__ int s_boff;
    int b = blockIdx.x, t = threadIdx.x;
    int ps = 0;
    for (int j = t; j < b; j += SCHUNK) ps += bsum[j];
    sd[t] = ps;
    __syncthreads();
    for (int off = SCHUNK / 2; off > 0; off >>= 1) {
        if (t < off) sd[t] += sd[t + off];
        __syncthreads();
    }
    if (t == 0) s_boff = sd[0];
    __syncthreads();
    int boff = s_boff;
    int i = b * SCHUNK + t;
    int v = (i < n) ? deg[i] : 0;
    sd[t] = v;
    __syncthreads();
    for (int off = 1; off < SCHUNK; off <<= 1) {
        int add = (t >= off) ? sd[t - off] : 0;
        __syncthreads();
        sd[t] += add;
        __syncthreads();
    }
    if (i < n) {
        rowstart[i] = boff + sd[t] - v;
        dinv[i] = rsqrtf((float)(v + 1));
    }
    if (b == nb - 1 && t == SCHUNK - 1) rowstart[n] = boff + sd[t];
}

// ---------------------------------------------------- quantized row helpers
__device__ __forceinline__ f32x2 dec_msg(const unsigned char* p) {
#if HAVE_FP4
    unsigned b = *p;
    return __builtin_amdgcn_cvt_scalef32_pk_f32_fp4(b, 1.0f, 0);
#else
    unsigned short u = *(const unsigned short*)p;
    return __builtin_amdgcn_cvt_pk_f32_fp8((int)u, false);
#endif
}

__device__ __forceinline__ unsigned enc_fp4_pair(float a, float b) {
#if HAVE_FP4
    return __builtin_amdgcn_cvt_scalef32_pk_fp4_f32(0u, a, b, 1.0f, 0);
#else
    (void)a; (void)b; return 0u;
#endif
}

__device__ __forceinline__ unsigned char enc_fp8(float sv) {
    int w = __builtin_amdgcn_cvt_pk_fp8_f32(sv, sv, 0, false);
    return (unsigned char)(w & 0xff);
}

#define QSTORE(sv_, gr_, cc_, cl_)                                             \
    {                                                                          \
        float sv = (sv_);                                                      \
        if (HAVE_FP4) {                                                        \
            float pv = __shfl_xor(sv, 1);                                      \
            if ((gr_) < n && !((cl_) & 1)) {                                   \
                unsigned pb = enc_fp4_pair(sv, pv);                            \
                Yq[((size_t)(gr_) << QSHIFT) + ((cc_) >> 1)] =                 \
                    (unsigned char)(pb & 0xff);                                \
            }                                                                  \
        } else {                                                               \
            if ((gr_) < n) {                                                   \
                Yq[((size_t)(gr_) << QSHIFT) + (cc_)] = enc_fp8(sv);           \
            }                                                                  \
        }                                                                      \
    }

// ---------------------- fused: GEMM layer-1 (MFMA, f32 in) + CSR scatter
__global__ __launch_bounds__(256) void gemm1_scatter_kernel(
        const float* __restrict__ Xf, const f16* __restrict__ Wh,
        const float* __restrict__ dinv, unsigned char* __restrict__ Yq,
        int n, int gemmBlocks, float qs,
        const void* ei, const int* __restrict__ posbuf,
        const int* __restrict__ rowstart, unsigned* __restrict__ selist,
        long long E) {
    __shared__ f16 wT[HDIM][HDIM + 8];
    int t = threadIdx.x;
    if ((int)blockIdx.x >= gemmBlocks) {
        int is64 = detect64(ei);
        long long e =
            (long long)((int)blockIdx.x - gemmBlocks) * blockDim.x + t;
        if (e >= E) return;
        int r = posbuf[e];
        if (r < 0) return;
        int d = load_idx(ei, E, 1, e, is64);
        int s = load_idx(ei, E, 0, e, is64);
        if ((unsigned)s >= (unsigned)n) s = d;
        long long pos = (long long)rowstart[d] + r;
        if (pos >= 0 && pos < E) selist[pos] = (unsigned)s << QSHIFT;
        return;
    }
    {
        int k = t >> 1, c0 = (t & 1) * 64;
        const f16x8* src = (const f16x8*)(Wh + (size_t)k * HDIM + c0);
#pragma unroll
        for (int j = 0; j < 8; ++j) {
            f16x8 v = src[j];
#pragma unroll
            for (int e = 0; e < 8; ++e) wT[c0 + j * 8 + e][k] = v[e];
        }
    }
    __syncthreads();
    int wid = t >> 6, lane = t & 63;
    int cl = lane & 15, kg = lane >> 4;
    int row0 = blockIdx.x * 64 + wid * 16;
    int rA = row0 + cl;
    bool okA = rA < n;
    f32x4 acc[8];
#pragma unroll
    for (int c = 0; c < 8; ++c) acc[c] = (f32x4){0.f, 0.f, 0.f, 0.f};
#pragma unroll
    for (int ks = 0; ks < 4; ++ks) {
        f16x8 a;
        if (okA) {
            const float* ap = Xf + (size_t)rA * HDIM + kg * 8 + ks * 32;
            float4 v0 = *(const float4*)ap;
            float4 v1 = *(const float4*)(ap + 4);
            a = (f16x8){(f16)v0.x, (f16)v0.y, (f16)v0.z, (f16)v0.w,
                        (f16)v1.x, (f16)v1.y, (f16)v1.z, (f16)v1.w};
        } else {
#pragma unroll
            for (int e = 0; e < 8; ++e) a[e] = (f16)0.f;
        }
#pragma unroll
        for (int c = 0; c < 8; ++c) {
            f16x8 b = *(const f16x8*)(&wT[c * 16 + cl][ks * 32 + kg * 8]);
            acc[c] = __builtin_amdgcn_mfma_f32_16x16x32_f16(a, b, acc[c], 0, 0, 0);
        }
    }
    int orow = row0 + kg * 4;
    float dv[4];
#pragma unroll
    for (int j = 0; j < 4; ++j)
        dv[j] = (orow + j < n) ? dinv[orow + j] * qs : 0.f;
#pragma unroll
    for (int c = 0; c < 8; ++c) {
#pragma unroll
        for (int j = 0; j < 4; ++j) {
            int gr = orow + j;
            QSTORE(acc[c][j] * dv[j], gr, c * 16 + cl, cl);
        }
    }
}

// -------------------------------------------- MFMA GEMM layer 2 (fp16 in)
__global__ __launch_bounds__(256) void gemm2_mfma_kernel(
        const f16* __restrict__ Xh, const f16* __restrict__ Wh,
        const float* __restrict__ dinv, unsigned char* __restrict__ Yq,
        int n, float qs) {
    __shared__ f16 wT[HDIM][HDIM + 8];
    int t = threadIdx.x;
    {
        int k = t >> 1, c0 = (t & 1) * 64;
        const f16x8* src = (const f16x8*)(Wh + (size_t)k * HDIM + c0);
#pragma unroll
        for (int j = 0; j < 8; ++j) {
            f16x8 v = src[j];
#pragma unroll
            for (int e = 0; e < 8; ++e) wT[c0 + j * 8 + e][k] = v[e];
        }
    }
    __syncthreads();
    int wid = t >> 6, lane = t & 63;
    int cl = lane & 15, kg = lane >> 4;
    int row0 = blockIdx.x * 64 + wid * 16;
    int rA = row0 + cl;
    bool okA = rA < n;
    f32x4 acc[8];
#pragma unroll
    for (int c = 0; c < 8; ++c) acc[c] = (f32x4){0.f, 0.f, 0.f, 0.f};
#pragma unroll
    for (int ks = 0; ks < 4; ++ks) {
        f16x8 a;
        if (okA) {
            a = *(const f16x8*)(Xh + (size_t)rA * HDIM + kg * 8 + ks * 32);
        } else {
#pragma unroll
            for (int e = 0; e < 8; ++e) a[e] = (f16)0.f;
        }
#pragma unroll
        for (int c = 0; c < 8; ++c) {
            f16x8 b = *(const f16x8*)(&wT[c * 16 + cl][ks * 32 + kg * 8]);
            acc[c] = __builtin_amdgcn_mfma_f32_16x16x32_f16(a, b, acc[c], 0, 0, 0);
        }
    }
    int orow = row0 + kg * 4;
    float dv[4];
#pragma unroll
    for (int j = 0; j < 4; ++j)
        dv[j] = (orow + j < n) ? dinv[orow + j] * qs : 0.f;
#pragma unroll
    for (int c = 0; c < 8; ++c) {
#pragma unroll
        for (int j = 0; j < 4; ++j) {
            int gr = orow + j;
            QSTORE(acc[c][j] * dv[j], gr, c * 16 + cl, cl);
        }
    }
}

// --------------------------------------- paired gather (2 nodes per wave)
#if HAVE_FP4
#define LOFF(lane) ((unsigned)(lane))
#else
#define LOFF(lane) ((unsigned)(lane) * 2u)
#endif

#define BATCH8(acc_, accb_, ii_)                                               \
    {                                                                          \
        const unsigned char* p[8];                                             \
        _Pragma("unroll") for (int j = 0; j < 8; ++j)                          \
            p[j] = Yq + selist[(ii_) + j] + loff;                              \
        f32x2 f0 = dec_msg(p[0]), f1 = dec_msg(p[1]);                          \
        f32x2 f2 = dec_msg(p[2]), f3 = dec_msg(p[3]);                          \
        f32x2 f4 = dec_msg(p[4]), f5 = dec_msg(p[5]);                         \
        f32x2 f6 = dec_msg(p[6]), f7 = dec_msg(p[7]);                         \
        acc_ += (f0 + f1) + (f2 + f3);                                         \
        accb_ += (f4 + f5) + (f6 + f7);                                        \
    }

__device__ __forceinline__ void gather_pair(
        const unsigned char* __restrict__ Yq, const int* __restrict__ rowstart,
        const unsigned* __restrict__ selist, int v0, int v1, int lane,
        f32x2* r0, f32x2* r1) {
    unsigned loff = LOFF(lane);
    f32x2 a0 = dec_msg(Yq + ((size_t)v0 << QSHIFT) + loff);
    f32x2 b0 = (f32x2){0.f, 0.f};
    f32x2 a1 = dec_msg(Yq + ((size_t)v1 << QSHIFT) + loff);
    f32x2 b1 = (f32x2){0.f, 0.f};
    int i0 = __builtin_amdgcn_readfirstlane(rowstart[v0]);
    int e0 = __builtin_amdgcn_readfirstlane(rowstart[v0 + 1]);
    int i1 = __builtin_amdgcn_readfirstlane(rowstart[v1]);
    int e1 = __builtin_amdgcn_readfirstlane(rowstart[v1 + 1]);
    while (i0 + 8 <= e0 && i1 + 8 <= e1) {
        const unsigned char* p0[8];
        const unsigned char* p1[8];
#pragma unroll
        for (int j = 0; j < 8; ++j) p0[j] = Yq + selist[i0 + j] + loff;
#pragma unroll
        for (int j = 0; j < 8; ++j) p1[j] = Yq + selist[i1 + j] + loff;
        f32x2 f0 = dec_msg(p0[0]), f1 = dec_msg(p0[1]);
        f32x2 f2 = dec_msg(p0[2]), f3 = dec_msg(p0[3]);
        f32x2 f4 = dec_msg(p0[4]), f5 = dec_msg(p0[5]);
        f32x2 f6 = dec_msg(p0[6]), f7 = dec_msg(p0[7]);
        f32x2 g0 = dec_msg(p1[0]), g1 = dec_msg(p1[1]);
        f32x2 g2 = dec_msg(p1[2]), g3 = dec_msg(p1[3]);
        f32x2 g4 = dec_msg(p1[4]), g5 = dec_msg(p1[5]);
        f32x2 g6 = dec_msg(p1[6]), g7 = dec_msg(p1[7]);
        a0 += (f0 + f1) + (f2 + f3);
        b0 += (f4 + f5) + (f6 + f7);
        a1 += (g0 + g1) + (g2 + g3);
        b1 += (g4 + g5) + (g6 + g7);
        i0 += 8;
        i1 += 8;
    }
    for (; i0 + 8 <= e0; i0 += 8) BATCH8(a0, b0, i0);
    for (; i0 < e0; ++i0) a0 += dec_msg(Yq + selist[i0] + loff);
    for (; i1 + 8 <= e1; i1 += 8) BATCH8(a1, b1, i1);
    for (; i1 < e1; ++i1) a1 += dec_msg(Yq + selist[i1] + loff);
    *r0 = a0 + b0;
    *r1 = a1 + b1;
}

// -------------------------------------------------------------------- pull
__global__ __launch_bounds__(256) void pull_relu_kernel(
        const unsigned char* __restrict__ Yq, const int* __restrict__ rowstart,
        const unsigned* __restrict__ selist, const float* __restrict__ dinv,
        const float* __restrict__ bias, __half* __restrict__ Bh, int n,
        float qinv) {
    int pw = (int)((blockIdx.x * blockDim.x + threadIdx.x) >> 6);
    int lane = threadIdx.x & 63;
    int v0 = pw * 2, v1 = pw * 2 + 1;
    if (v0 >= n) return;
    bool has1 = v1 < n;
    f32x2 a0, a1;
    gather_pair(Yq, rowstart, selist, v0, has1 ? v1 : v0, lane, &a0, &a1);
    float2 b = ((const float2*)bias)[lane];
    {
        float dv = dinv[v0] * qinv;
        float hx = fmaxf(fmaf(dv, a0.x, b.x), 0.f);
        float hy = fmaxf(fmaf(dv, a0.y, b.y), 0.f);
        ((__half2*)(Bh + (size_t)v0 * HDIM))[lane] = __floats2half2_rn(hx, hy);
    }
    if (has1) {
        float dv = dinv[v1] * qinv;
        float hx = fmaxf(fmaf(dv, a1.x, b.x), 0.f);
        float hy = fmaxf(fmaf(dv, a1.y, b.y), 0.f);
        ((__half2*)(Bh + (size_t)v1 * HDIM))[lane] = __floats2half2_rn(hx, hy);
    }
}

// ------------------------------------------- fused pull (layer 2) + heads
#define SENT (-3.0e38f)
#define BFLY(p) \
    p += __shfl_xor(p, 32); p += __shfl_xor(p, 16); p += __shfl_xor(p, 8); \
    p += __shfl_xor(p, 4);  p += __shfl_xor(p, 2);  p += __shfl_xor(p, 1);

__device__ __forceinline__ void heads_write(
        float hx, float hy, int v, int lane, float4 wd, float4 wu,
        float4 wr0, float4 wr1, const float* __restrict__ bdet,
        const float* __restrict__ bund, const float* __restrict__ broot,
        float* __restrict__ out, int n) {
    float pd0 = hx * wd.x + hy * wd.z;
    float pd1 = hx * wd.y + hy * wd.w;
    float pu0 = hx * wu.x + hy * wu.z;
    float pu1 = hx * wu.y + hy * wu.w;
    float pr0 = hx * wr0.x + hy * wr1.x;
    float pr1 = hx * wr0.y + hy * wr1.y;
    float pr2 = hx * wr0.z + hy * wr1.z;
    float pr3 = hx * wr0.w + hy * wr1.w;
    BFLY(pd0); BFLY(pd1); BFLY(pu0); BFLY(pu1);
    BFLY(pr0); BFLY(pr1); BFLY(pr2); BFLY(pr3);
    if (lane == 0) {
        float d0 = pd0 + bdet[0], d1 = pd1 + bdet[1];
        float u0 = pu0 + bund[0], u1 = pu1 + bund[1];
        float r0 = pr0 + broot[0], r1 = pr1 + broot[1];
        float r2 = pr2 + broot[2], r3 = pr3 + broot[3];
        float m = fmaxf(d0, d1);
        float lse = m + logf(expf(d0 - m) + expf(d1 - m));
        out[(size_t)v * 2 + 0] = fin(d0 - lse);
        out[(size_t)v * 2 + 1] = fin(d1 - lse);
        float* ro = out + 2 * (size_t)n + (size_t)v * 5;
        if (d1 > d0) {  // argmax == 1 (tie -> index 0 -> false)
            float mm = fmaxf(fmaxf(r0, r1), fmaxf(r2, r3));
            float l2 = mm + logf(expf(r0 - mm) + expf(r1 - mm) +
                                 expf(r2 - mm) + expf(r3 - mm));
            ro[0] = SENT;  // reference: -inf (finite sentinel, inf-inf=nan)
            ro[1] = fin(r0 - l2);
            ro[2] = fin(r1 - l2);
            ro[3] = fin(r2 - l2);
            ro[4] = fin(r3 - l2);
        } else {
            float mm = fmaxf(u0, u1);
            float l2 = mm + logf(expf(u0 - mm) + expf(u1 - mm));
            ro[0] = fin(u0 - l2);
            ro[1] = fin(u1 - l2);
            ro[2] = SENT;
            ro[3] = SENT;
            ro[4] = SENT;
        }
    }
}

__global__ __launch_bounds__(256) void pull_heads_kernel(
        const unsigned char* __restrict__ Yq, const int* __restrict__ rowstart,
        const unsigned* __restrict__ selist, const float* __restrict__ dinv,
        const float* __restrict__ bias,
        const float* __restrict__ Wdet, const float* __restrict__ bdet,
        const float* __restrict__ Wund, const float* __restrict__ bund,
        const float* __restrict__ Wroot, const float* __restrict__ broot,
        float* __restrict__ out, int n, float qinv) {
    int pw = (int)((blockIdx.x * blockDim.x + threadIdx.x) >> 6);
    int lane = threadIdx.x & 63;
    int v0 = pw * 2, v1 = pw * 2 + 1;
    if (v0 >= n) return;
    bool has1 = v1 < n;
    f32x2 a0, a1;
    gather_pair(Yq, rowstart, selist, v0, has1 ? v1 : v0, lane, &a0, &a1);
    float2 b = ((const float2*)bias)[lane];
    float4 wd  = ((const float4*)Wdet)[lane];
    float4 wu  = ((const float4*)Wund)[lane];
    float4 wr0 = ((const float4*)Wroot)[2 * lane];
    float4 wr1 = ((const float4*)Wroot)[2 * lane + 1];
    {
        float dv = dinv[v0] * qinv;
        float hx = fmaxf(fmaf(dv, a0.x, b.x), 0.f);
        float hy = fmaxf(fmaf(dv, a0.y, b.y), 0.f);
        heads_write(hx, hy, v0, lane, wd, wu, wr0, wr1, bdet, bund, broot,
                    out, n);
    }
    if (has1) {
        float dv = dinv[v1] * qinv;
        float hx = fmaxf(fmaf(dv, a1.x, b.x), 0.f);
        float hy = fmaxf(fmaf(dv, a1.y, b.y), 0.f);
        heads_write(hx, hy, v1, lane, wd, wu, wr0, wr1, bdet, bund, broot,
                    out, n);
    }
}

__global__ void ws_too_small_kernel(float* out, int n) {
    int i = blockIdx.x * blockDim.x + threadIdx.x;
    if (i < n) out[i] = -12345.0f;  // sentinel: workspace was insufficient
}

// ----------------------------------------------------------------- launch
extern "C" void kernel_launch(void* const* d_in, const int* in_sizes, int n_in,
                              void* d_out, int out_size, void* d_ws,
                              size_t ws_size, hipStream_t stream) {
    const float* x     = (const float*)d_in[0];
    const void*  ei    = d_in[1];
    const float* W1    = (const float*)d_in[2];
    const float* b1    = (const float*)d_in[3];
    const float* W2    = (const float*)d_in[4];
    const float* b2    = (const float*)d_in[5];
    const float* Wdet  = (const float*)d_in[6];
    const float* bdet  = (const float*)d_in[7];
    const float* Wund  = (const float*)d_in[8];
    const float* bund  = (const float*)d_in[9];
    const float* Wroot = (const float*)d_in[10];
    const float* broot = (const float*)d_in[11];
    int N = in_sizes[0] / HDIM;       // 50000
    long long E = in_sizes[1] / 2;    // 800000
    float* out = (float*)d_out;
    int nb = (N + SCHUNK - 1) / SCHUNK;

    size_t off = 0;
    auto carve = [&](size_t bytes) -> void* {
        void* p = (char*)d_ws + off;
        off += (bytes + 255) & ~(size_t)255;
        return p;
    };
    unsigned char* Yq   = (unsigned char*)carve((size_t)N * HDIM);
    __half*   Bh       = (__half*)carve((size_t)N * HDIM * 2);
    f16*      W1h      = (f16*)carve((size_t)HDIM * HDIM * 2);
    f16*      W2h      = (f16*)carve((size_t)HDIM * HDIM * 2);
    float*    dinv     = (float*)carve((size_t)N * 4);
    int*      rowstart = (int*)carve((size_t)(N + 1) * 4);
    int*      wcur     = (int*)carve((size_t)N * 4);
    int*      posbuf   = (int*)carve((size_t)E * 4);
    unsigned* selist   = (unsigned*)carve((size_t)E * 4);
    int*      bsum     = (int*)carve((size_t)nb * 4);

    if (off > ws_size) {
        ws_too_small_kernel<<<(out_size + 255) / 256, 256, 0, stream>>>(out, out_size);
        return;
    }

    int e1grid = (int)((E + 255) / 256);
    int gemm_grid = (N + 63) / 64;
    int pairs = (N + 1) / 2;
    int pull_grid = (pairs + 3) / 4;  // 4 waves (node pairs) per block

    // CSR pass A (+ W cvt fused)
    hipMemsetAsync(wcur, 0, (size_t)N * 4, stream);
    pos_cvt_kernel<<<e1grid + 32, 256, 0, stream>>>(ei, wcur, posbuf, E, N,
                                                    e1grid, W1, W2, W1h, W2h);
    scan_p1_kernel<<<nb, SCHUNK, 0, stream>>>(wcur, bsum, N);
    scan_p23_kernel<<<nb, SCHUNK, 0, stream>>>(wcur, bsum, nb, rowstart,
                                               dinv, N);

    // layer-1 GEMM + CSR pass B fused (independent; overlap)
    gemm1_scatter_kernel<<<gemm_grid + e1grid, 256, 0, stream>>>(
        x, W1h, dinv, Yq, N, gemm_grid, QS1, ei, posbuf, rowstart, selist, E);

    // layer 1 pull (2 nodes/wave)
    pull_relu_kernel<<<pull_grid, 256, 0, stream>>>(Yq, rowstart, selist,
                                                    dinv, b1, Bh, N, QI1);
    // layer 2 GEMM + fused pull + heads -> out
    gemm2_mfma_kernel<<<gemm_grid, 256, 0, stream>>>((const f16*)Bh, W2h,
                                                     dinv, Yq, N, QS2);
    pull_heads_kernel<<<pull_grid, 256, 0, stream>>>(Yq, rowstart, selist,
                                                     dinv, b2, Wdet, bdet,
                                                     Wund, bund, Wroot, broot,
                                                     out, N, QI2);
}